// Round 4
// baseline (431.673 us; speedup 1.0000x reference)
//
#include <hip/hip_runtime.h>
#include <hip/hip_bf16.h>
#include <utility>

typedef __bf16        bf16x8 __attribute__((ext_vector_type(8)));
typedef float         f32x16 __attribute__((ext_vector_type(16)));
typedef unsigned int  u32x2  __attribute__((ext_vector_type(2)));
typedef unsigned int   u32;
typedef unsigned short u16;

template<int N> using IC = std::integral_constant<int, N>;

__device__ __forceinline__ u16 f32_to_bf16(float f) {
    u32 u = __builtin_bit_cast(u32, f);
    u = (u + 0x7FFFu + ((u >> 16) & 1u)) >> 16;
    return (u16)u;
}
__device__ __forceinline__ u32 pack2bf(float a, float b) {
    return (u32)f32_to_bf16(a) | ((u32)f32_to_bf16(b) << 16);
}

// ---------------- kernel 1: build conv weights, bf16, layout [tap][oc][ic]
__global__ void build_c(const float* __restrict__ wxx,
                        const float* __restrict__ wid,
                        const float* __restrict__ XX,
                        const float* __restrict__ ident,
                        const int*   __restrict__ indsxx,
                        const int*   __restrict__ indsid,
                        u16*         __restrict__ cb)
{
    int idx = blockIdx.x * 256 + threadIdx.x;          // 25*128*128 = 409600
    if (idx >= 25 * 128 * 128) return;
    int b = idx & 127;            // ic2
    int a = (idx >> 7) & 127;     // oc2
    int t = idx >> 14;            // kh*5+kw
    int w2 = (a >> 1) * 64 + (b >> 1);
    float v = wxx[w2 * 5 + indsxx[t]] * XX[(a * 128 + b) * 25 + t]
            + ident[a * 128 + b]      * wid[w2 * 6 + indsid[t]];
    cb[idx] = f32_to_bf16(v);
}

// ---------------- kernel 2: implicit-GEMM conv, 32x32x16 bf16 MFMA
// 512 thr = 8 waves (2 oc-halves x 4 w-quarters). Block: 128 oc x 4 rows x 128 w.
// 8 phases of 16 ic. LDS: dbuf [8 rows][128 wp][48B], odd chunk-stride => bank-clean reads.
constexpr int LDSROW = 128 * 48;       // 6144 B per staged row
constexpr int LDSBUF = 8 * LDSROW;     // 49152 B per buffer
constexpr int ZOFF   = 2 * LDSBUF;     // 16B zero chunk for OOB w-halo

__global__ void __launch_bounds__(512, 2)
conv_mfma(const float* __restrict__ x,
          const u16*   __restrict__ cb,
          float*       __restrict__ out)
{
    __shared__ unsigned char lds[2 * LDSBUF + 64];

    const int tid    = threadIdx.x;
    const int lane   = tid & 63;
    const int wv     = tid >> 6;
    const int wave_m = wv & 1;                           // oc half
    const int wave_q = wv >> 1;                          // w quarter 0..3
    const int l31    = lane & 31;
    const int h2     = lane >> 5;                        // k-half within K=16

    // bijective XCD swizzle: 512 blocks, 64 consecutive tiles per XCD
    const int bid  = blockIdx.x;
    const int sbid = (bid & 7) * 64 + (bid >> 3);
    const int bb   = sbid >> 5;                          // batch
    const int h0   = (sbid & 31) << 2;                   // output row base

    // staging map: thread -> (w column, ic quad)
    const int wc  = tid & 127;
    const int icO = tid >> 7;                            // 0..3 -> 4 ic each

    if (tid < 16) *reinterpret_cast<u32*>(&lds[ZOFF + tid * 4]) = 0u;

    f32x16 acc[2][4];
    #pragma unroll
    for (int i = 0; i < 2; ++i)
        #pragma unroll
        for (int j = 0; j < 4; ++j)
            #pragma unroll
            for (int k = 0; k < 16; ++k) acc[i][j][k] = 0.f;

    float  pf[2][4];                                     // one staging pair in flight
    bf16x8 A[2][5][2];                                   // A dbuf [parity][kh][m]

    const float* xbase = x + (size_t)bb * (128 * 128 * 128) + wc;
    const u16*   cbA   = cb + wave_m * 8192 + l31 * 128 + h2 * 8;

    auto ALOAD = [&](auto PARc, int kw, int ph) {
        constexpr int P = decltype(PARc)::value;
        const u16* base = cbA + kw * 16384 + ph * 16;
        #pragma unroll
        for (int kh = 0; kh < 5; ++kh) {
            A[P][kh][0] = *reinterpret_cast<const bf16x8*>(base + kh * 81920);
            A[P][kh][1] = *reinterpret_cast<const bf16x8*>(base + kh * 81920 + 4096);
        }
    };

    auto ISSUE = [&](int p, int icb) {                   // icb = phase ic base
        #pragma unroll
        for (int r = 0; r < 2; ++r) {
            const int hp = h0 - 2 + 2 * p + r;
            if ((unsigned)hp < 128u) {
                const float* px = xbase + (size_t)(icb + icO * 4) * 16384 + hp * 128;
                #pragma unroll
                for (int j = 0; j < 4; ++j) pf[r][j] = px[(size_t)j * 16384];
            } else {
                #pragma unroll
                for (int j = 0; j < 4; ++j) pf[r][j] = 0.f;
            }
        }
    };

    auto WRITE = [&](int p, int wbuf) {
        #pragma unroll
        for (int r = 0; r < 2; ++r) {
            u32x2 v;
            v[0] = pack2bf(pf[r][0], pf[r][1]);
            v[1] = pack2bf(pf[r][2], pf[r][3]);
            *reinterpret_cast<u32x2*>(&lds[wbuf * LDSBUF + (2 * p + r) * LDSROW
                                           + wc * 48 + icO * 8]) = v;
        }
    };

    // prologue: stage phase 0 into buf 0; load A(ph0, kw0) into parity 0
    #pragma unroll
    for (int p = 0; p < 4; ++p) { ISSUE(p, 0); WRITE(p, 0); }
    ALOAD(IC<0>{}, 0, 0);
    __syncthreads();

    auto PHASE = [&](auto P0c, int ph) {
        constexpr int P0 = decltype(P0c)::value;         // = ph & 1 = read buffer
        auto STEP = [&](auto KWc) {
            constexpr int KW  = decltype(KWc)::value;
            constexpr int PAR = (P0 + KW) & 1;
            constexpr int NXT = PAR ^ 1;
            // A prefetch for next step (next kw, or next phase's kw0)
            if (!(ph == 7 && KW == 4)) {
                if constexpr (KW == 4) ALOAD(IC<NXT>{}, 0, ph + 1);
                else                   ALOAD(IC<NXT>{}, KW + 1, ph);
            }
            if (ph < 7 && KW < 4) ISSUE(KW, (ph + 1) * 16);
            // B reads + MFMA stencil
            const int wpx = wave_q * 32 + l31 + KW - 2;
            const unsigned char* bbase = ((unsigned)wpx < 128u)
                ? &lds[P0 * LDSBUF + wpx * 48 + h2 * 16]
                : &lds[ZOFF];
            const int rstep = ((unsigned)wpx < 128u) ? LDSROW : 0;
            __builtin_amdgcn_s_setprio(1);
            #pragma unroll
            for (int rp = 0; rp < 8; ++rp) {
                const bf16x8 b = *reinterpret_cast<const bf16x8*>(bbase + rp * rstep);
                #pragma unroll
                for (int kh = 0; kh < 5; ++kh) {
                    const int n = rp - kh;
                    if (0 <= n && n < 4) {
                        acc[0][n] = __builtin_amdgcn_mfma_f32_32x32x16_bf16(A[PAR][kh][0], b, acc[0][n], 0, 0, 0);
                        acc[1][n] = __builtin_amdgcn_mfma_f32_32x32x16_bf16(A[PAR][kh][1], b, acc[1][n], 0, 0, 0);
                    }
                }
            }
            __builtin_amdgcn_s_setprio(0);
            if (ph < 7 && KW < 4) WRITE(KW, (ph + 1) & 1);
        };
        STEP(IC<0>{}); STEP(IC<1>{}); STEP(IC<2>{}); STEP(IC<3>{}); STEP(IC<4>{});
    };

    #pragma unroll 1
    for (int ip = 0; ip < 4; ++ip) {
        PHASE(IC<0>{}, 2 * ip);
        __syncthreads();
        PHASE(IC<1>{}, 2 * ip + 1);
        __syncthreads();
    }

    // epilogue: D frag (32x32): col=lane&31 -> w, row=(reg&3)+8*(reg>>2)+4*h2 -> oc
    const int wpix = wave_q * 32 + l31;
    #pragma unroll
    for (int m = 0; m < 2; ++m)
        #pragma unroll
        for (int reg = 0; reg < 16; ++reg) {
            const int oc = wave_m * 64 + m * 32 + (reg & 3) + ((reg >> 2) << 3) + (h2 << 2);
            float* op = out + ((size_t)(bb * 128 + oc) * 128 + h0) * 128 + wpix;
            #pragma unroll
            for (int n = 0; n < 4; ++n)
                op[n * 128] = acc[m][n][reg];
        }
}

extern "C" void kernel_launch(void* const* d_in, const int* in_sizes, int n_in,
                              void* d_out, int out_size, void* d_ws, size_t ws_size,
                              hipStream_t stream)
{
    const float* x    = (const float*)d_in[0];
    const float* wxx  = (const float*)d_in[1];
    const float* wi   = (const float*)d_in[2];
    const float* XX   = (const float*)d_in[3];
    const float* iden = (const float*)d_in[4];
    const int*   ixx  = (const int*)d_in[5];
    const int*   iid  = (const int*)d_in[6];

    u16* cbuf = (u16*)d_ws;                              // 819200 B scratch

    build_c<<<1600, 256, 0, stream>>>(wxx, wi, XX, iden, ixx, iid, cbuf);
    conv_mfma<<<512, 512, 0, stream>>>(x, cbuf, (float*)d_out);
}

// Round 6
// 248.648 us; speedup vs baseline: 1.7361x; 1.7361x over previous
//
#include <hip/hip_runtime.h>
#include <hip/hip_bf16.h>
#include <utility>

typedef __bf16        bf16x8 __attribute__((ext_vector_type(8)));
typedef float         f32x16 __attribute__((ext_vector_type(16)));
typedef unsigned int  u32x4  __attribute__((ext_vector_type(4)));
typedef unsigned int   u32;
typedef unsigned short u16;

template<int N> using IC = std::integral_constant<int, N>;

__device__ __forceinline__ u16 f32_to_bf16(float f) {
    u32 u = __builtin_bit_cast(u32, f);
    u = (u + 0x7FFFu + ((u >> 16) & 1u)) >> 16;
    return (u16)u;
}
__device__ __forceinline__ u32 pack2bf(float a, float b) {
    return (u32)f32_to_bf16(a) | ((u32)f32_to_bf16(b) << 16);
}

// ---------------- kernel 1: build conv weights, bf16, layout [tap][oc][ic]
__global__ void build_c(const float* __restrict__ wxx,
                        const float* __restrict__ wid,
                        const float* __restrict__ XX,
                        const float* __restrict__ ident,
                        const int*   __restrict__ indsxx,
                        const int*   __restrict__ indsid,
                        u16*         __restrict__ cb)
{
    int idx = blockIdx.x * 256 + threadIdx.x;          // 25*128*128 = 409600
    if (idx >= 25 * 128 * 128) return;
    int b = idx & 127;            // ic2
    int a = (idx >> 7) & 127;     // oc2
    int t = idx >> 14;            // kh*5+kw
    int w2 = (a >> 1) * 64 + (b >> 1);
    float v = wxx[w2 * 5 + indsxx[t]] * XX[(a * 128 + b) * 25 + t]
            + ident[a * 128 + b]      * wid[w2 * 6 + indsid[t]];
    cb[idx] = f32_to_bf16(v);
}

// ---------------- kernel 2: implicit-GEMM conv, 32x32x16 bf16 MFMA
// 512 thr = 8 waves (2 oc-halves x 4 w-quarters). Block: 128 oc x 4 rows x 128 w.
// 8 stages of 16 ic (one K=16 MFMA step each). Stencil B-reuse: 8 LDS reads -> 40 MFMAs.
// LDS rows: [8 rows][128 wp][48 B] (32 B data + 16 pad): ds_read/write_b128 bank-minimal.
constexpr int LDSROW = 128 * 48;       // 6144 B
constexpr int LDSBUF = 8 * LDSROW;     // 49152 B
constexpr int ZOFF   = 2 * LDSBUF;     // 16 B zero chunk for OOB w-halo

__global__ void __launch_bounds__(512, 1)
conv_mfma(const float* __restrict__ x,
          const u16*   __restrict__ cb,
          float*       __restrict__ out)
{
    __shared__ unsigned char lds[2 * LDSBUF + 16];

    const int tid    = threadIdx.x;
    const int lane   = tid & 63;
    const int wv     = tid >> 6;
    const int wave_m = wv & 1;                           // oc half of 128
    const int wave_q = wv >> 1;                          // w quarter 0..3
    const int l31    = lane & 31;
    const int h2     = lane >> 5;                        // k-half within K=16

    // bijective XCD swizzle: 512 blocks, 64 consecutive tiles per XCD
    const int bid  = blockIdx.x;
    const int sbid = (bid & 7) * 64 + (bid >> 3);
    const int bb   = sbid >> 5;                          // batch
    const int h0   = (sbid & 31) << 2;                   // output row base

    // staging map: thread -> (w column, 8-ic half, row parity)
    const int wc  = tid & 127;
    const int ic8 = (tid >> 7) & 1;
    const int rh  = tid >> 8;                            // 0/1

    if (tid < 4) *reinterpret_cast<u32*>(&lds[ZOFF + tid * 4]) = 0u;

    f32x16 acc[2][4];                                    // [oc 32-half][output row]
    #pragma unroll
    for (int i = 0; i < 2; ++i)
        #pragma unroll
        for (int j = 0; j < 4; ++j)
            #pragma unroll
            for (int k = 0; k < 16; ++k) acc[i][j][k] = 0.f;

    float pf[4][8];                                      // 4 in-flight units x 8 ic

    const float* xbase = x + (size_t)bb * (128 * 16384) + wc;
    const u16*   cbA0  = cb + (wave_m * 64 + l31) * 128 + h2 * 8;
    const int    wpx_b = wave_q * 32 + l31 - 2;

    // ISSUE unit U of stage s: row h0-2+2U+rh, ic plane s*16+ic8*8 .. +8
    auto ISSUE = [&](auto Uc, int s) {
        constexpr int U = decltype(Uc)::value;
        const int hp = h0 - 2 + 2 * U + rh;
        if ((unsigned)hp < 128u) {
            const float* px = xbase + (size_t)(s * 16 + ic8 * 8) * 16384 + hp * 128;
            #pragma unroll
            for (int j = 0; j < 8; ++j) pf[U][j] = px[(size_t)j * 16384];
        } else {
            #pragma unroll
            for (int j = 0; j < 8; ++j) pf[U][j] = 0.f;
        }
    };

    auto WRITE = [&](auto Uc, int wbuf) {
        constexpr int U = decltype(Uc)::value;
        u32x4 v;
        v[0] = pack2bf(pf[U][0], pf[U][1]);
        v[1] = pack2bf(pf[U][2], pf[U][3]);
        v[2] = pack2bf(pf[U][4], pf[U][5]);
        v[3] = pack2bf(pf[U][6], pf[U][7]);
        *reinterpret_cast<u32x4*>(&lds[wbuf * LDSBUF + (2 * U + rh) * LDSROW
                                       + wc * 48 + ic8 * 16]) = v;
    };

    // pure compute cluster: A-loads (L2) + 8 B-reads -> 40 MFMAs
    auto CLUSTER = [&](auto KWc, int s) {
        constexpr int KW = decltype(KWc)::value;
        const u16* abase = cbA0 + KW * 16384 + s * 16;
        bf16x8 A[5][2];
        #pragma unroll
        for (int kh = 0; kh < 5; ++kh) {
            A[kh][0] = *reinterpret_cast<const bf16x8*>(abase + kh * 81920);
            A[kh][1] = *reinterpret_cast<const bf16x8*>(abase + kh * 81920 + 4096);
        }
        const int wpx  = wpx_b + KW;
        const bool vld = (unsigned)wpx < 128u;
        const unsigned char* lbase = vld ? &lds[(s & 1) * LDSBUF + wpx * 48 + h2 * 16]
                                         : &lds[ZOFF];
        const int rstep = vld ? LDSROW : 0;
        __builtin_amdgcn_s_setprio(1);
        #pragma unroll
        for (int rp = 0; rp < 8; ++rp) {
            const bf16x8 b = *reinterpret_cast<const bf16x8*>(lbase + rp * rstep);
            #pragma unroll
            for (int kh = 0; kh < 5; ++kh) {
                const int n = rp - kh;
                if (0 <= n && n < 4) {
                    acc[0][n] = __builtin_amdgcn_mfma_f32_32x32x16_bf16(A[kh][0], b, acc[0][n], 0, 0, 0);
                    acc[1][n] = __builtin_amdgcn_mfma_f32_32x32x16_bf16(A[kh][1], b, acc[1][n], 0, 0, 0);
                }
            }
        }
        __builtin_amdgcn_s_setprio(0);
    };

    // prologue: stage 0 into buf 0
    ISSUE(IC<0>{}, 0); ISSUE(IC<1>{}, 0); ISSUE(IC<2>{}, 0); ISSUE(IC<3>{}, 0);
    WRITE(IC<0>{}, 0); WRITE(IC<1>{}, 0); WRITE(IC<2>{}, 0); WRITE(IC<3>{}, 0);
    __syncthreads();

    #pragma unroll 1
    for (int s = 0; s < 8; ++s) {
        const int nb = (s + 1) & 1;
        if (s < 7) {                                     // issue next stage (32 loads in flight)
            ISSUE(IC<0>{}, s + 1); ISSUE(IC<1>{}, s + 1);
            ISSUE(IC<2>{}, s + 1); ISSUE(IC<3>{}, s + 1);
        }
        CLUSTER(IC<0>{}, s);
        if (s < 7) WRITE(IC<0>{}, nb);
        CLUSTER(IC<1>{}, s);
        if (s < 7) WRITE(IC<1>{}, nb);
        CLUSTER(IC<2>{}, s);
        if (s < 7) WRITE(IC<2>{}, nb);
        CLUSTER(IC<3>{}, s);
        if (s < 7) WRITE(IC<3>{}, nb);
        CLUSTER(IC<4>{}, s);
        __syncthreads();
    }

    // epilogue: D frag (32x32): col=lane&31 -> w, row=(reg&3)+8*(reg>>2)+4*h2 -> oc
    const int wpix = wave_q * 32 + l31;
    #pragma unroll
    for (int m = 0; m < 2; ++m)
        #pragma unroll
        for (int reg = 0; reg < 16; ++reg) {
            const int oc = wave_m * 64 + m * 32 + (reg & 3) + ((reg >> 2) << 3) + (h2 << 2);
            float* op = out + ((size_t)(bb * 128 + oc) * 128 + h0) * 128 + wpix;
            #pragma unroll
            for (int n = 0; n < 4; ++n)
                op[n * 128] = acc[m][n][reg];
        }
}

extern "C" void kernel_launch(void* const* d_in, const int* in_sizes, int n_in,
                              void* d_out, int out_size, void* d_ws, size_t ws_size,
                              hipStream_t stream)
{
    const float* x    = (const float*)d_in[0];
    const float* wxx  = (const float*)d_in[1];
    const float* wi   = (const float*)d_in[2];
    const float* XX   = (const float*)d_in[3];
    const float* iden = (const float*)d_in[4];
    const int*   ixx  = (const int*)d_in[5];
    const int*   iid  = (const int*)d_in[6];

    u16* cbuf = (u16*)d_ws;                              // 819200 B scratch

    build_c<<<1600, 256, 0, stream>>>(wxx, wi, XX, iden, ixx, iid, cbuf);
    conv_mfma<<<512, 512, 0, stream>>>(x, cbuf, (float*)d_out);
}

// Round 7
// 245.920 us; speedup vs baseline: 1.7553x; 1.0111x over previous
//
#include <hip/hip_runtime.h>
#include <hip/hip_bf16.h>
#include <utility>

typedef __bf16        bf16x8 __attribute__((ext_vector_type(8)));
typedef float         f32x16 __attribute__((ext_vector_type(16)));
typedef unsigned int  u32x4  __attribute__((ext_vector_type(4)));
typedef unsigned int   u32;
typedef unsigned short u16;

template<int N> using IC = std::integral_constant<int, N>;

__device__ __forceinline__ u16 f32_to_bf16(float f) {
    u32 u = __builtin_bit_cast(u32, f);
    u = (u + 0x7FFFu + ((u >> 16) & 1u)) >> 16;
    return (u16)u;
}
__device__ __forceinline__ u32 pack2bf(float a, float b) {
    return (u32)f32_to_bf16(a) | ((u32)f32_to_bf16(b) << 16);
}

// ---------------- kernel 1: build conv weights, bf16, layout [tap][oc][ic]
__global__ void build_c(const float* __restrict__ wxx,
                        const float* __restrict__ wid,
                        const float* __restrict__ XX,
                        const float* __restrict__ ident,
                        const int*   __restrict__ indsxx,
                        const int*   __restrict__ indsid,
                        u16*         __restrict__ cb)
{
    int idx = blockIdx.x * 256 + threadIdx.x;          // 25*128*128 = 409600
    if (idx >= 25 * 128 * 128) return;
    int b = idx & 127;            // ic2
    int a = (idx >> 7) & 127;     // oc2
    int t = idx >> 14;            // kh*5+kw
    int w2 = (a >> 1) * 64 + (b >> 1);
    float v = wxx[w2 * 5 + indsxx[t]] * XX[(a * 128 + b) * 25 + t]
            + ident[a * 128 + b]      * wid[w2 * 6 + indsid[t]];
    cb[idx] = f32_to_bf16(v);
}

// ---------------- kernel 2: implicit-GEMM conv, 32x32x16 bf16 MFMA
// 256 thr = 4 waves (2 oc-halves x 2 w-quarters). Block: 128 oc x 4 rows x 64 w.
// 52 KB LDS -> 2 independent blocks/CU (decoupled barriers hide latency).
// 8 stages of 16 ic. Stencil B-reuse: 8 LDS reads -> 40 MFMAs per cluster.
// LDS rows: [8 rows][68 wp][48 B] (32 B data + 16 pad): b128 r/w bank-minimal;
// w-halo (+-2) staged, so hot loop has no bounds logic.
constexpr int LDSROW = 68 * 48;        // 3264 B
constexpr int LDSBUF = 8 * LDSROW;     // 26112 B

__global__ void __launch_bounds__(256, 2)
conv_mfma(const float* __restrict__ x,
          const u16*   __restrict__ cb,
          float*       __restrict__ out)
{
    __shared__ unsigned char lds[2 * LDSBUF];

    const int tid    = threadIdx.x;
    const int lane   = tid & 63;
    const int wv     = tid >> 6;
    const int wave_m = wv & 1;                           // oc half of 128
    const int wave_q = wv >> 1;                          // w half of 64
    const int l31    = lane & 31;
    const int h2     = lane >> 5;                        // k-half within K=16

    // bijective XCD swizzle: 1024 blocks, 128 consecutive tiles per XCD
    const int bid  = blockIdx.x;
    const int sbid = (bid & 7) * 128 + (bid >> 3);
    const int bb   = sbid >> 6;                          // batch
    const int tile = sbid & 63;
    const int h0   = (tile >> 1) << 2;                   // output row base
    const int w0   = (tile & 1) << 6;                    // output col base

    // staging map (main 64 cols): thread -> (w col, 8-ic half, row parity)
    const int wc  = tid & 63;
    const int ic8 = (tid >> 6) & 1;
    const int rh  = tid >> 7;                            // 0/1

    // halo map (threads 0..63): 4 cols x 2 ic8 x 8 rows
    const int hsel  = tid & 3;                           // 0..3
    const int wcolH = (hsel < 2) ? (hsel - 2) : (62 + hsel);   // -2,-1,64,65
    const int ic8H  = (tid >> 2) & 1;
    const int rH    = tid >> 3;                          // 0..7 (tid<64)
    const int hIdxH = wcolH + 2;                         // 0,1,66,67

    f32x16 acc[2][4];                                    // [oc 32-half][output row]
    #pragma unroll
    for (int i = 0; i < 2; ++i)
        #pragma unroll
        for (int j = 0; j < 4; ++j)
            #pragma unroll
            for (int k = 0; k < 16; ++k) acc[i][j][k] = 0.f;

    float pf[4][8];                                      // 4 in-flight main units
    float pfh[8];                                        // halo unit

    const float* xbase = x + (size_t)bb * (128 * 16384);
    const u16*   cbA0  = cb + (wave_m * 64 + l31) * 128 + h2 * 8;

    auto ISSUE = [&](auto Uc, int s) {                   // main unit U of stage s
        constexpr int U = decltype(Uc)::value;
        const int hp = h0 - 2 + 2 * U + rh;
        if ((unsigned)hp < 128u) {
            const float* px = xbase + (size_t)(s * 16 + ic8 * 8) * 16384 + hp * 128 + w0 + wc;
            #pragma unroll
            for (int j = 0; j < 8; ++j) pf[U][j] = px[(size_t)j * 16384];
        } else {
            #pragma unroll
            for (int j = 0; j < 8; ++j) pf[U][j] = 0.f;
        }
    };

    auto ISSUEH = [&](int s) {                           // halo unit (tid<64)
        if (tid < 64) {
            const int hp = h0 - 2 + rH;
            const int gc = w0 + wcolH;
            if ((unsigned)hp < 128u && (unsigned)gc < 128u) {
                const float* px = xbase + (size_t)(s * 16 + ic8H * 8) * 16384 + hp * 128 + gc;
                #pragma unroll
                for (int j = 0; j < 8; ++j) pfh[j] = px[(size_t)j * 16384];
            } else {
                #pragma unroll
                for (int j = 0; j < 8; ++j) pfh[j] = 0.f;
            }
        }
    };

    auto WRITE = [&](auto Uc, int wbuf) {
        constexpr int U = decltype(Uc)::value;
        u32x4 v;
        v[0] = pack2bf(pf[U][0], pf[U][1]);
        v[1] = pack2bf(pf[U][2], pf[U][3]);
        v[2] = pack2bf(pf[U][4], pf[U][5]);
        v[3] = pack2bf(pf[U][6], pf[U][7]);
        *reinterpret_cast<u32x4*>(&lds[wbuf * LDSBUF + (2 * U + rh) * LDSROW
                                       + (wc + 2) * 48 + ic8 * 16]) = v;
    };

    auto WRITEH = [&](int wbuf) {
        if (tid < 64) {
            u32x4 v;
            v[0] = pack2bf(pfh[0], pfh[1]);
            v[1] = pack2bf(pfh[2], pfh[3]);
            v[2] = pack2bf(pfh[4], pfh[5]);
            v[3] = pack2bf(pfh[6], pfh[7]);
            *reinterpret_cast<u32x4*>(&lds[wbuf * LDSBUF + rH * LDSROW
                                           + hIdxH * 48 + ic8H * 16]) = v;
        }
    };

    // pure compute cluster: A-loads (L2) + 8 B-reads -> 40 MFMAs
    auto CLUSTER = [&](auto KWc, int s) {
        constexpr int KW = decltype(KWc)::value;
        const u16* abase = cbA0 + KW * 16384 + s * 16;
        bf16x8 A[5][2];
        #pragma unroll
        for (int kh = 0; kh < 5; ++kh) {
            A[kh][0] = *reinterpret_cast<const bf16x8*>(abase + kh * 81920);
            A[kh][1] = *reinterpret_cast<const bf16x8*>(abase + kh * 81920 + 4096);
        }
        const unsigned char* lbase = &lds[(s & 1) * LDSBUF
                                          + (wave_q * 32 + l31 + KW) * 48 + h2 * 16];
        __builtin_amdgcn_s_setprio(1);
        #pragma unroll
        for (int rp = 0; rp < 8; ++rp) {
            const bf16x8 b = *reinterpret_cast<const bf16x8*>(lbase + rp * LDSROW);
            #pragma unroll
            for (int kh = 0; kh < 5; ++kh) {
                const int n = rp - kh;
                if (0 <= n && n < 4) {
                    acc[0][n] = __builtin_amdgcn_mfma_f32_32x32x16_bf16(A[kh][0], b, acc[0][n], 0, 0, 0);
                    acc[1][n] = __builtin_amdgcn_mfma_f32_32x32x16_bf16(A[kh][1], b, acc[1][n], 0, 0, 0);
                }
            }
        }
        __builtin_amdgcn_s_setprio(0);
    };

    // prologue: stage 0 into buf 0
    ISSUE(IC<0>{}, 0); ISSUE(IC<1>{}, 0); ISSUE(IC<2>{}, 0); ISSUE(IC<3>{}, 0); ISSUEH(0);
    WRITE(IC<0>{}, 0); WRITE(IC<1>{}, 0); WRITE(IC<2>{}, 0); WRITE(IC<3>{}, 0); WRITEH(0);
    __syncthreads();

    #pragma unroll 1
    for (int s = 0; s < 8; ++s) {
        const int nb = (s + 1) & 1;
        if (s < 7) {                                     // next stage's loads in flight
            ISSUE(IC<0>{}, s + 1); ISSUE(IC<1>{}, s + 1);
            ISSUE(IC<2>{}, s + 1); ISSUE(IC<3>{}, s + 1); ISSUEH(s + 1);
        }
        CLUSTER(IC<0>{}, s);
        if (s < 7) WRITE(IC<0>{}, nb);
        CLUSTER(IC<1>{}, s);
        if (s < 7) WRITE(IC<1>{}, nb);
        CLUSTER(IC<2>{}, s);
        if (s < 7) WRITE(IC<2>{}, nb);
        CLUSTER(IC<3>{}, s);
        if (s < 7) { WRITE(IC<3>{}, nb); WRITEH(nb); }
        CLUSTER(IC<4>{}, s);
        __syncthreads();
    }

    // epilogue: D frag (32x32): col=lane&31 -> w, row=(reg&3)+8*(reg>>2)+4*h2 -> oc
    const int wpix = w0 + wave_q * 32 + l31;
    #pragma unroll
    for (int m = 0; m < 2; ++m)
        #pragma unroll
        for (int reg = 0; reg < 16; ++reg) {
            const int oc = wave_m * 64 + m * 32 + (reg & 3) + ((reg >> 2) << 3) + (h2 << 2);
            float* op = out + ((size_t)(bb * 128 + oc) * 128 + h0) * 128 + wpix;
            #pragma unroll
            for (int n = 0; n < 4; ++n)
                op[n * 128] = acc[m][n][reg];
        }
}

extern "C" void kernel_launch(void* const* d_in, const int* in_sizes, int n_in,
                              void* d_out, int out_size, void* d_ws, size_t ws_size,
                              hipStream_t stream)
{
    const float* x    = (const float*)d_in[0];
    const float* wxx  = (const float*)d_in[1];
    const float* wi   = (const float*)d_in[2];
    const float* XX   = (const float*)d_in[3];
    const float* iden = (const float*)d_in[4];
    const int*   ixx  = (const int*)d_in[5];
    const int*   iid  = (const int*)d_in[6];

    u16* cbuf = (u16*)d_ws;                              // 819200 B scratch

    build_c<<<1600, 256, 0, stream>>>(wxx, wi, XX, iden, ixx, iid, cbuf);
    conv_mfma<<<1024, 256, 0, stream>>>(x, cbuf, (float*)d_out);
}